// Round 1
// baseline (1223.411 us; speedup 1.0000x reference)
//
#include <hip/hip_runtime.h>

#define BATCH 16
#define CI 64
#define CO 64
#define H 128
#define W 128
#define HO 126
#define WO 126

#define CO_B 8     // output channels per block
#define TH 32      // tile rows
#define TW 64      // tile cols
#define PX 8       // output cols per thread
#define XROWS 34   // TH+2
#define XCOLS 66   // TW+2
#define XS 67      // LDS row stride (floats): bank = (3r+8cg) mod 32 -> 2-way only
#define WSTRIDE 12 // pad 9 -> 12 for alignment

__launch_bounds__(256, 4)
__global__ void dynconv_direct(const float* __restrict__ x,
                               const float* __restrict__ w,
                               const float* __restrict__ bias,
                               float* __restrict__ out) {
    __shared__ float x_s[XROWS * XS];            // 9,112 B
    __shared__ float w_s[CO_B * CI * WSTRIDE];   // 24,576 B

    const int tid = threadIdx.x;
    const int x0  = blockIdx.x * TW;             // 0, 64
    const int y0  = blockIdx.y * TH;             // 0, 32, 64, 96
    const int bz  = blockIdx.z;                  // b*8 + co_group
    const int b   = bz >> 3;
    const int co0 = (bz & 7) * CO_B;

    // ---- stage weights for this (b, co-group): 8*64*9 = 4608 consecutive floats
    const float* wg = w + ((size_t)(b * CO + co0)) * (CI * 9);
    for (int i = tid; i < CO_B * CI * 9; i += 256) {
        int co = i / (CI * 9);
        int r2 = i - co * (CI * 9);
        int ci = r2 / 9;
        int k  = r2 - ci * 9;
        w_s[(co * CI + ci) * WSTRIDE + k] = wg[i];
    }

    const int r = tid >> 3;          // 0..31: output row within tile
    const int c = (tid & 7) * PX;    // 0..56: first output col within tile

    float acc[CO_B][PX];
    #pragma unroll
    for (int co = 0; co < CO_B; ++co)
        #pragma unroll
        for (int p = 0; p < PX; ++p) acc[co][p] = 0.f;

    const float* xb = x + (size_t)b * CI * H * W;

    for (int ci = 0; ci < CI; ++ci) {
        __syncthreads();   // protect x_s from previous iteration's readers
        // ---- stage x window rows y0..y0+33, cols x0..x0+65 (zero OOB)
        const float* xp = xb + (size_t)ci * H * W;
        for (int i = tid; i < XROWS * XCOLS; i += 256) {
            int row = i / XCOLS;
            int col = i - row * XCOLS;
            int gy = y0 + row, gx = x0 + col;
            float v = 0.f;
            if (gy < H && gx < W) v = xp[gy * W + gx];
            x_s[row * XS + col] = v;
        }
        __syncthreads();

        #pragma unroll
        for (int dy = 0; dy < 3; ++dy) {
            float xrow[PX + 2];
            #pragma unroll
            for (int j = 0; j < PX + 2; ++j)
                xrow[j] = x_s[(r + dy) * XS + c + j];
            #pragma unroll
            for (int co = 0; co < CO_B; ++co) {
                #pragma unroll
                for (int dx = 0; dx < 3; ++dx) {
                    float wv = w_s[(co * CI + ci) * WSTRIDE + dy * 3 + dx];
                    #pragma unroll
                    for (int p = 0; p < PX; ++p)
                        acc[co][p] += xrow[dx + p] * wv;
                }
            }
        }
    }

    // ---- epilogue: bias + store
    const int oy = y0 + r;
    if (oy < HO) {
        #pragma unroll
        for (int co = 0; co < CO_B; ++co) {
            const float bv = bias[b * CO + co0 + co];
            float* op = out + (((size_t)(b * CO + co0 + co)) * HO + oy) * (size_t)WO + x0 + c;
            #pragma unroll
            for (int p = 0; p < PX; ++p) {
                if (x0 + c + p < WO) op[p] = acc[co][p] + bv;
            }
        }
    }
}

extern "C" void kernel_launch(void* const* d_in, const int* in_sizes, int n_in,
                              void* d_out, int out_size, void* d_ws, size_t ws_size,
                              hipStream_t stream) {
    const float* x    = (const float*)d_in[0];
    const float* wgt  = (const float*)d_in[1];
    const float* bias = (const float*)d_in[2];
    float* out        = (float*)d_out;

    dim3 grid(2 /*ceil(126/64)*/, 4 /*ceil(126/32)*/, BATCH * (CO / CO_B));
    dim3 block(256);
    dynconv_direct<<<grid, block, 0, stream>>>(x, wgt, bias, out);
}

// Round 2
// 159.120 us; speedup vs baseline: 7.6886x; 7.6886x over previous
//
#include <hip/hip_runtime.h>

#define BATCH 16
#define CI 64
#define CO 64
#define H 128
#define W 128
#define HO 126
#define WO 126

typedef short bfrag __attribute__((ext_vector_type(8)));   // 8 bf16 = 4 VGPRs
typedef float ffrag __attribute__((ext_vector_type(4)));   // 4 fp32 acc

static __device__ __forceinline__ unsigned short f2bf(float f) {
    unsigned u = __float_as_uint(f);
    u += 0x7fffu + ((u >> 16) & 1u);      // RNE
    return (unsigned short)(u >> 16);
}

// prepass: w[b][co][ci][dy][dx] fp32 -> w_t[b][s][co][ci] bf16  (s = dy*3+dx)
__global__ void wt_prepass(const float* __restrict__ w, unsigned short* __restrict__ w_t) {
    int i = blockIdx.x * 256 + threadIdx.x;          // linear over w_t, 589824 total
    int ci = i & 63;
    int co = (i >> 6) & 63;
    int bs = i >> 12;                                // b*9+s
    int b = bs / 9, s = bs - b * 9;
    w_t[i] = f2bf(w[(((b * 64 + co) * 64 + ci) * 9) + s]);
}

// x_t chunk swizzle: 16B chunk at (row, col, ci-octet o):
//   chunk = ((row*128+col)*8) + (o ^ (col&7) ^ ((row&1)<<2))
// -> B-frag ds_read_b128 conflict-free; staging writes ~4-way.
static __device__ __forceinline__ int xchunk(int row, int col, int o) {
    return ((row << 7) + col) * 8 + (o ^ (col & 7) ^ ((row & 1) << 2));
}

__launch_bounds__(256, 2)
__global__ void dynconv_mfma(const float* __restrict__ x,
                             const unsigned short* __restrict__ w_t,
                             const float* __restrict__ bias,
                             float* __restrict__ out) {
    __shared__ __align__(16) unsigned short x_t[4 * 128 * 64];  // 64 KB, swizzled [row][col][ci]
    __shared__ __align__(16) unsigned short A_lds[64 * 64];     // 8 KB, swizzled [co][ci]

    const int tid = threadIdx.x;
    const int rg  = blockIdx.x;        // 0..62  (2 output rows each)
    const int b   = blockIdx.y;
    const int y0  = rg * 2;

    const int wave = tid >> 6;
    const int lane = tid & 63;
    const int l16  = lane & 15;
    const int lq   = lane >> 4;        // quad 0..3
    const int wm   = wave & 1;         // co half
    const int wn   = wave >> 1;        // output row (n>>7)

    // ---- stage x_t: x rows y0..y0+3 (always in-bounds: y0<=124), all 64 ci, bf16
    {
        const float* xb = x + (size_t)b * CI * H * W;
        #pragma unroll
        for (int it = 0; it < 16; ++it) {
            int item = it * 256 + tid;             // 4096 items: (cp, row, colq)
            int colq = item & 31;
            int row  = (item >> 5) & 3;
            int cp   = item >> 7;                  // ci pair index 0..31
            const float* p = xb + ((size_t)(2 * cp) * H + (y0 + row)) * W + colq * 4;
            float4 f0 = *(const float4*)p;
            float4 f1 = *(const float4*)(p + H * W);
            int o = cp >> 2;
            int e = (2 * cp) & 7;
            #pragma unroll
            for (int jj = 0; jj < 4; ++jj) {
                int j = (jj + colq) & 3;           // diagonal: spread col&7 across lanes
                int col = colq * 4 + j;
                float a0 = (&f0.x)[j], a1 = (&f1.x)[j];
                *(unsigned int*)&x_t[xchunk(row, col, o) * 8 + e] =
                    (unsigned int)f2bf(a0) | ((unsigned int)f2bf(a1) << 16);
            }
        }
    }

    ffrag acc[2][8];
    #pragma unroll
    for (int mt = 0; mt < 2; ++mt)
        #pragma unroll
        for (int nt = 0; nt < 8; ++nt)
            acc[mt][nt] = (ffrag){0.f, 0.f, 0.f, 0.f};

    const bfrag* gw = (const bfrag*)w_t + (size_t)(b * 9) * 512;  // 512 chunks of 16B per shift
    bfrag w0 = gw[2 * tid];
    bfrag w1 = gw[2 * tid + 1];

    for (int s = 0; s < 9; ++s) {
        const int dy = s / 3, dx = s - dy * 3;
        __syncthreads();   // protect A_lds from previous shift's readers
        {   // store this shift's A tile (swizzled [co][ci] octets)
            int co_s = tid >> 2;
            int o0 = (tid & 3) * 2;
            *(bfrag*)&A_lds[(co_s * 8 + (o0 ^ (co_s & 7))) * 8] = w0;
            *(bfrag*)&A_lds[(co_s * 8 + ((o0 + 1) ^ (co_s & 7))) * 8] = w1;
        }
        if (s < 8) {       // prefetch next shift's weights (hidden under compute)
            w0 = gw[(s + 1) * 512 + 2 * tid];
            w1 = gw[(s + 1) * 512 + 2 * tid + 1];
        }
        __syncthreads();

        const int xr = wn + dy;        // staged x row 0..3
        #pragma unroll
        for (int ks = 0; ks < 2; ++ks) {
            const int o = ks * 4 + lq; // ci octet for this lane's k-slice
            bfrag a0, a1;
            {
                int co_a = wm * 32 + l16;
                a0 = *(const bfrag*)&A_lds[(co_a * 8 + (o ^ (co_a & 7))) * 8];
                co_a += 16;
                a1 = *(const bfrag*)&A_lds[(co_a * 8 + (o ^ (co_a & 7))) * 8];
            }
            #pragma unroll
            for (int nt = 0; nt < 8; ++nt) {
                int colx = nt * 16 + l16 + dx;
                if (colx > 127) colx = 127;        // cols 126/127 are discarded outputs
                bfrag bf = *(const bfrag*)&x_t[xchunk(xr, colx, o) * 8];
                acc[0][nt] = __builtin_amdgcn_mfma_f32_16x16x32_bf16(a0, bf, acc[0][nt], 0, 0, 0);
                acc[1][nt] = __builtin_amdgcn_mfma_f32_16x16x32_bf16(a1, bf, acc[1][nt], 0, 0, 0);
            }
        }
    }

    // ---- epilogue: bias + store (C/D: col = lane&15, row = quad*4 + reg)
    const int oy = y0 + wn;            // <= 125, always valid
    #pragma unroll
    for (int mt = 0; mt < 2; ++mt) {
        #pragma unroll
        for (int r = 0; r < 4; ++r) {
            int co = wm * 32 + mt * 16 + lq * 4 + r;
            float bv = bias[b * 64 + co];
            float* op = out + ((size_t)(b * 64 + co) * HO + oy) * WO;
            #pragma unroll
            for (int nt = 0; nt < 8; ++nt) {
                int ox = nt * 16 + l16;
                if (ox < WO) op[ox] = acc[mt][nt][r] + bv;
            }
        }
    }
}

extern "C" void kernel_launch(void* const* d_in, const int* in_sizes, int n_in,
                              void* d_out, int out_size, void* d_ws, size_t ws_size,
                              hipStream_t stream) {
    const float* x    = (const float*)d_in[0];
    const float* w    = (const float*)d_in[1];
    const float* bias = (const float*)d_in[2];
    float* out        = (float*)d_out;
    unsigned short* w_t = (unsigned short*)d_ws;   // 589824 * 2 B = 1.18 MB

    wt_prepass<<<dim3(589824 / 256), dim3(256), 0, stream>>>(w, w_t);
    dynconv_mfma<<<dim3(63, BATCH), dim3(256), 0, stream>>>(x, w_t, bias, out);
}

// Round 3
// 151.874 us; speedup vs baseline: 8.0555x; 1.0477x over previous
//
#include <hip/hip_runtime.h>

#define BATCH 16
#define CI 64
#define CO 64
#define H 128
#define W 128
#define HO 126
#define WO 126

typedef short bfrag __attribute__((ext_vector_type(8)));   // 8 bf16 = 4 VGPRs
typedef float ffrag __attribute__((ext_vector_type(4)));   // 4 fp32 acc

#define AS3(p) ((__attribute__((address_space(3))) void*)(p))
#define AS1(p) ((const __attribute__((address_space(1))) void*)(p))

static __device__ __forceinline__ unsigned short f2bf(float f) {
    unsigned u = __float_as_uint(f);
    u += 0x7fffu + ((u >> 16) & 1u);      // RNE
    return (unsigned short)(u >> 16);
}

// prepass: w[b][co][ci][dy][dx] fp32 -> w_t[b][s][co][ci] bf16  (s = dy*3+dx)
__global__ void wt_prepass(const float* __restrict__ w, unsigned short* __restrict__ w_t) {
    int i = blockIdx.x * 256 + threadIdx.x;          // 589824 total
    int ci = i & 63;
    int co = (i >> 6) & 63;
    int bs = i >> 12;
    int b = bs / 9, s = bs - b * 9;
    w_t[i] = f2bf(w[(((b * 64 + co) * 64 + ci) * 9) + s]);
}

// prepass: x[b][ci][y][col] fp32 -> x_tg bf16, per (b,y) row-slab of 1024 16B chunks:
//   chunk (col, o) holds ci = o*8..o*8+7, stored at index col*8 + (o ^ (col&7))
//   (swizzle baked into GLOBAL layout so lane-linear DMA lands it in LDS as-is)
__global__ void xt_prepass(const float* __restrict__ x, unsigned short* __restrict__ x_tg) {
    __shared__ float tile[64 * 32 * 4];   // 64 ci x 32 float4-slots, slot swizzled: 32 KB
    const int tid = threadIdx.x;
    const int y = blockIdx.x;
    const int b = blockIdx.y;

    const float* xp = x + (size_t)b * CI * H * W + (size_t)y * W;
    #pragma unroll
    for (int p = 0; p < 8; ++p) {
        int item = p * 256 + tid;          // (ci, colq): 64*32 = 2048
        int colq = item & 31;
        int ci   = item >> 5;
        float4 v = *(const float4*)(xp + (size_t)ci * H * W + colq * 4);
        int slot = colq ^ (ci >> 3);       // f4-slot swizzle -> conflict-free both phases
        *(float4*)&tile[(ci * 32 + slot) * 4] = v;
    }
    __syncthreads();

    unsigned short* og = x_tg + ((size_t)(b * 128 + y)) * 1024 * 8;
    #pragma unroll
    for (int q = 0; q < 4; ++q) {
        int item = q * 256 + tid;          // (col, o): 128*8 = 1024 chunks
        int o   = item & 7;
        int col = item >> 3;
        unsigned short u[8];
        #pragma unroll
        for (int e = 0; e < 8; ++e) {
            int ci = o * 8 + e;
            u[e] = f2bf(tile[(ci * 32 + ((col >> 2) ^ o)) * 4 + (col & 3)]);
        }
        int chunk = col * 8 + (o ^ (col & 7));
        *(uint4*)&og[chunk * 8] = *(const uint4*)u;
    }
}

__launch_bounds__(256, 2)
__global__ void dynconv_mfma(const unsigned short* __restrict__ x_tg,
                             const unsigned short* __restrict__ w_t,
                             const float* __restrict__ bias,
                             float* __restrict__ out) {
    __shared__ __align__(16) unsigned short xs[4 * 8192];   // 4 row-slabs x 16 KB = 64 KB

    const int tid  = threadIdx.x;
    const int rg   = blockIdx.x;       // 0..62, 2 output rows each
    const int b    = blockIdx.y;
    const int y0   = rg * 2;
    const int wave = tid >> 6;
    const int lane = tid & 63;
    const int l16  = lane & 15;
    const int lq   = lane >> 4;
    const int wm   = wave & 1;         // co half
    const int wn   = wave >> 1;        // output row within tile

    // ---- DMA stage: wave copies its row-slab (16 KB) global->LDS, 16 x 1KB
    {
        const unsigned short* gsrc = x_tg + ((size_t)(b * 128 + y0 + wave)) * 8192;
        #pragma unroll
        for (int i = 0; i < 16; ++i) {
            __builtin_amdgcn_global_load_lds(AS1(gsrc + i * 512 + lane * 8),
                                             AS3(xs + wave * 8192 + i * 512),
                                             16, 0, 0);
        }
    }

    // ---- A-frag prefetch for shift 0 (w_t is L2-resident, 4 KB per (b,s,co-half))
    const bfrag* wtb = (const bfrag*)w_t + (size_t)(b * 9) * 512;   // 512 chunks/shift
    const int co_b = wm * 32 + l16;
    bfrag acur[4], anxt[4];
    #pragma unroll
    for (int ks = 0; ks < 2; ++ks)
        #pragma unroll
        for (int mt = 0; mt < 2; ++mt)
            acur[ks * 2 + mt] = wtb[(co_b + mt * 16) * 8 + ks * 4 + lq];

    ffrag acc[2][8];
    #pragma unroll
    for (int mt = 0; mt < 2; ++mt)
        #pragma unroll
        for (int nt = 0; nt < 8; ++nt)
            acc[mt][nt] = (ffrag){0.f, 0.f, 0.f, 0.f};

    __syncthreads();   // the only barrier: DMA complete

    for (int s = 0; s < 9; ++s) {
        if (s < 8) {
            const bfrag* wn2 = wtb + (s + 1) * 512;
            #pragma unroll
            for (int ks = 0; ks < 2; ++ks)
                #pragma unroll
                for (int mt = 0; mt < 2; ++mt)
                    anxt[ks * 2 + mt] = wn2[(co_b + mt * 16) * 8 + ks * 4 + lq];
        }
        const int dy = s / 3, dx = s - dy * 3;
        const int xr = wn + dy;            // staged row-slab 0..3
        #pragma unroll
        for (int ks = 0; ks < 2; ++ks) {
            const int o = ks * 4 + lq;     // ci octet for this lane's k-slice
            #pragma unroll
            for (int nt = 0; nt < 8; ++nt) {
                int colx = nt * 16 + l16 + dx;
                if (colx > 127) colx = 127;            // clamped lanes -> discarded cols
                const bfrag bf = *(const bfrag*)&xs[xr * 8192 + (colx * 8 + (o ^ (colx & 7))) * 8];
                acc[0][nt] = __builtin_amdgcn_mfma_f32_16x16x32_bf16(acur[ks * 2 + 0], bf, acc[0][nt], 0, 0, 0);
                acc[1][nt] = __builtin_amdgcn_mfma_f32_16x16x32_bf16(acur[ks * 2 + 1], bf, acc[1][nt], 0, 0, 0);
            }
        }
        #pragma unroll
        for (int j = 0; j < 4; ++j) acur[j] = anxt[j];
    }

    // ---- epilogue: bias + store (C/D: col = lane&15, row = quad*4 + reg)
    const int oy = y0 + wn;                // <= 125
    #pragma unroll
    for (int mt = 0; mt < 2; ++mt) {
        #pragma unroll
        for (int r = 0; r < 4; ++r) {
            int co = wm * 32 + mt * 16 + lq * 4 + r;
            float bv = bias[b * 64 + co];
            float* op = out + ((size_t)(b * 64 + co) * HO + oy) * WO;
            #pragma unroll
            for (int nt = 0; nt < 8; ++nt) {
                int ox = nt * 16 + l16;
                if (ox < WO) op[ox] = acc[mt][nt][r] + bv;
            }
        }
    }
}

extern "C" void kernel_launch(void* const* d_in, const int* in_sizes, int n_in,
                              void* d_out, int out_size, void* d_ws, size_t ws_size,
                              hipStream_t stream) {
    const float* x    = (const float*)d_in[0];
    const float* w    = (const float*)d_in[1];
    const float* bias = (const float*)d_in[2];
    float* out        = (float*)d_out;

    unsigned short* w_t  = (unsigned short*)d_ws;                  // 1,179,648 B
    unsigned short* x_tg = (unsigned short*)((char*)d_ws + 1179648); // 33,554,432 B

    wt_prepass<<<dim3(589824 / 256), dim3(256), 0, stream>>>(w, w_t);
    xt_prepass<<<dim3(128, BATCH), dim3(256), 0, stream>>>(x, x_tg);
    dynconv_mfma<<<dim3(63, BATCH), dim3(256), 0, stream>>>(x_tg, w_t, bias, out);
}

// Round 4
// 141.378 us; speedup vs baseline: 8.6534x; 1.0742x over previous
//
#include <hip/hip_runtime.h>
#include <hip/hip_bf16.h>

#define BATCH 16
#define CI 64
#define CO 64
#define H 128
#define W 128
#define HO 126
#define WO 126

typedef short bfrag __attribute__((ext_vector_type(8)));   // 8 bf16 = 4 VGPRs
typedef float ffrag __attribute__((ext_vector_type(4)));   // 4 fp32 acc

static __device__ __forceinline__ unsigned short f2bf(float f) {
    unsigned u = __float_as_uint(f);
    u += 0x7fffu + ((u >> 16) & 1u);      // RNE
    return (unsigned short)(u >> 16);
}

// prepass: w[b][co][ci][dy][dx] fp32 -> w_t[b][s][co][ci] bf16  (s = dy*3+dx)
__global__ void wt_prepass(const float* __restrict__ w, unsigned short* __restrict__ w_t) {
    int i = blockIdx.x * 256 + threadIdx.x;          // 589824 total
    int ci = i & 63;
    int co = (i >> 6) & 63;
    int bs = i >> 12;
    int b = bs / 9, s = bs - b * 9;
    w_t[i] = f2bf(w[(((b * 64 + co) * 64 + ci) * 9) + s]);
}

// Fused: stage 4 x-rows (fp32 NCHW -> bf16 swizzled chunks in LDS), then 9
// shift-GEMMs with mfma_f32_16x16x32_bf16.  Chunk (col,o) holds ci o*8..o*8+7
// at slab index col*8 + (o ^ (col&7))  -> B-frag ds_read_b128 conflict-free
// (verified 0 conflicts in R3); staging ds_write_b128 is diagonal = 8 banks-
// cycles/KB = optimal.
__launch_bounds__(256, 2)
__global__ void dynconv_fused(const float* __restrict__ x,
                              const unsigned short* __restrict__ w_t,
                              const float* __restrict__ bias,
                              float* __restrict__ out) {
    __shared__ __align__(16) unsigned short xs[4 * 8192];   // 4 row-slabs x 16 KB

    const int tid  = threadIdx.x;
    const int rg   = blockIdx.x;       // 0..62, 2 output rows each
    const int b    = blockIdx.y;
    const int y0   = rg * 2;
    const int wave = tid >> 6;
    const int lane = tid & 63;
    const int l16  = lane & 15;
    const int lq   = lane >> 4;
    const int wm   = wave & 1;         // co half
    const int wn   = wave >> 1;        // output row within tile

    // ---- fused stage: gather 8 ci-strided fp32 per chunk, convert, scatter to LDS
    {
        const int col = tid & 127;     // lanes = consecutive cols -> coalesced loads
        const int h   = tid >> 7;      // ci half
        const float* xb = x + (size_t)b * CI * H * W + (size_t)y0 * W + col;
        #pragma unroll
        for (int row = 0; row < 4; ++row) {
            #pragma unroll
            for (int oc = 0; oc < 4; ++oc) {
                const int o = h * 4 + oc;
                const float* p = xb + (size_t)(o * 8) * (H * W) + row * W;
                unsigned int u[4];
                #pragma unroll
                for (int e = 0; e < 4; ++e) {
                    float f0 = p[(size_t)(2 * e) * (H * W)];
                    float f1 = p[(size_t)(2 * e + 1) * (H * W)];
                    __hip_bfloat162 h2 = __float22bfloat162_rn(make_float2(f0, f1));
                    u[e] = *(unsigned int*)&h2;          // low = f0 (ci even) ✓
                }
                *(uint4*)&xs[(row * 1024 + col * 8 + (o ^ (col & 7))) * 8] = *(const uint4*)u;
            }
        }
    }

    // ---- A-frag prefetch for shift 0 (w_t L2-resident)
    const bfrag* wtb = (const bfrag*)w_t + (size_t)(b * 9) * 512;   // 512 chunks/shift
    const int co_b = wm * 32 + l16;
    bfrag acur[4], anxt[4];
    #pragma unroll
    for (int ks = 0; ks < 2; ++ks)
        #pragma unroll
        for (int mt = 0; mt < 2; ++mt)
            acur[ks * 2 + mt] = wtb[(co_b + mt * 16) * 8 + ks * 4 + lq];

    ffrag acc[2][8];
    #pragma unroll
    for (int mt = 0; mt < 2; ++mt)
        #pragma unroll
        for (int nt = 0; nt < 8; ++nt)
            acc[mt][nt] = (ffrag){0.f, 0.f, 0.f, 0.f};

    __syncthreads();   // the only barrier: staging complete

    for (int s = 0; s < 9; ++s) {
        if (s < 8) {
            const bfrag* wn2 = wtb + (s + 1) * 512;
            #pragma unroll
            for (int ks = 0; ks < 2; ++ks)
                #pragma unroll
                for (int mt = 0; mt < 2; ++mt)
                    anxt[ks * 2 + mt] = wn2[(co_b + mt * 16) * 8 + ks * 4 + lq];
        }
        const int dy = s / 3, dx = s - dy * 3;
        const int xr = wn + dy;            // staged row-slab 0..3
        #pragma unroll
        for (int ks = 0; ks < 2; ++ks) {
            const int o = ks * 4 + lq;     // ci octet for this lane's k-slice
            #pragma unroll
            for (int nt = 0; nt < 8; ++nt) {
                int colx = nt * 16 + l16 + dx;
                if (colx > 127) colx = 127;            // clamped lanes -> discarded cols
                const bfrag bf = *(const bfrag*)&xs[xr * 8192 + (colx * 8 + (o ^ (colx & 7))) * 8];
                acc[0][nt] = __builtin_amdgcn_mfma_f32_16x16x32_bf16(acur[ks * 2 + 0], bf, acc[0][nt], 0, 0, 0);
                acc[1][nt] = __builtin_amdgcn_mfma_f32_16x16x32_bf16(acur[ks * 2 + 1], bf, acc[1][nt], 0, 0, 0);
            }
        }
        #pragma unroll
        for (int j = 0; j < 4; ++j) acur[j] = anxt[j];
    }

    // ---- epilogue: bias + store (C/D: col = lane&15, row = quad*4 + reg)
    const int oy = y0 + wn;                // <= 125
    #pragma unroll
    for (int mt = 0; mt < 2; ++mt) {
        #pragma unroll
        for (int r = 0; r < 4; ++r) {
            int co = wm * 32 + mt * 16 + lq * 4 + r;
            float bv = bias[b * 64 + co];
            float* op = out + ((size_t)(b * 64 + co) * HO + oy) * WO;
            #pragma unroll
            for (int nt = 0; nt < 8; ++nt) {
                int ox = nt * 16 + l16;
                if (ox < WO) op[ox] = acc[mt][nt][r] + bv;
            }
        }
    }
}

extern "C" void kernel_launch(void* const* d_in, const int* in_sizes, int n_in,
                              void* d_out, int out_size, void* d_ws, size_t ws_size,
                              hipStream_t stream) {
    const float* x    = (const float*)d_in[0];
    const float* w    = (const float*)d_in[1];
    const float* bias = (const float*)d_in[2];
    float* out        = (float*)d_out;

    unsigned short* w_t = (unsigned short*)d_ws;   // 1,179,648 B

    wt_prepass<<<dim3(589824 / 256), dim3(256), 0, stream>>>(w, w_t);
    dynconv_fused<<<dim3(63, BATCH), dim3(256), 0, stream>>>(x, w_t, bias, out);
}